// Round 1
// baseline (9212.943 us; speedup 1.0000x reference)
//
#include <hip/hip_runtime.h>
#include <hip/hip_bf16.h>

typedef __bf16 bf8_t __attribute__((ext_vector_type(8)));
typedef float  f4_t  __attribute__((ext_vector_type(4)));

#define SENT 0xFFFFFFFFu

__device__ __forceinline__ unsigned short f2bf(float f) {
    unsigned u = __float_as_uint(f);
    unsigned r = (u + 0x7fffu + ((u >> 16) & 1u)) >> 16;   // RNE
    return (unsigned short)r;
}
__device__ __forceinline__ float bflo(unsigned u) { return __uint_as_float(u << 16); }
__device__ __forceinline__ float bfhi(unsigned u) { return __uint_as_float(u & 0xffff0000u); }
__device__ __forceinline__ float sigm(float x) { return 1.f / (1.f + __expf(-x)); }

// ---------------- fill hs with sentinel ----------------
__global__ __launch_bounds__(256) void fill_sent(unsigned* __restrict__ hs) {
    uint4* p = (uint4*)(hs + (size_t)blockIdx.x * 1024);
    p[threadIdx.x] = make_uint4(SENT, SENT, SENT, SENT);
}

// ---------------- embedding gather ----------------
__global__ __launch_bounds__(256) void gather_emb(const int* __restrict__ sent,
                                                  const float* __restrict__ wte,
                                                  float* __restrict__ emb) {
    int srow = blockIdx.x;
    int v = sent[srow];
    const float4* src = (const float4*)(wte + (size_t)v * 1024);
    float4* dst = (float4*)(emb + (size_t)srow * 1024);
    dst[threadIdx.x] = src[threadIdx.x];
}

// ---------------- bf16 MFMA GEMM: C[M,N] = A[M,K] * B[N,K]^T + bias ----------------
// A, B fp32 in global; converted to bf16 during LDS staging.
// 128x128 tile, BK=32, 4 waves as 2x2 of 64x64, each wave 4x4 of 16x16x32 MFMA.
__global__ __launch_bounds__(256) void gemm_bt(const float* __restrict__ A,
                                               const float* __restrict__ B,
                                               const float* __restrict__ bias0,
                                               const float* __restrict__ bias1,
                                               float* __restrict__ C,
                                               int M, int N, int K) {
    __shared__ unsigned short As[128][40];   // pitch 40 (+8 pad)
    __shared__ unsigned short Bs[128][40];
    const int tid  = threadIdx.x;
    const int lane = tid & 63;
    const int wave = tid >> 6;
    const int wm = wave >> 1, wn = wave & 1;
    const int m0 = blockIdx.x * 128, n0 = blockIdx.y * 128;
    const int lr = tid >> 3;            // staging row 0..31
    const int lc = tid & 7;             // staging float4 col 0..7
    const int frow = lane & 15;         // fragment row
    const int fk = (lane >> 4) << 3;    // fragment k offset (0,8,16,24)

    f4_t acc[4][4];
#pragma unroll
    for (int i = 0; i < 4; i++)
#pragma unroll
        for (int j = 0; j < 4; j++)
            acc[i][j] = f4_t{0.f, 0.f, 0.f, 0.f};

    for (int k0 = 0; k0 < K; k0 += 32) {
#pragma unroll
        for (int i = 0; i < 4; i++) {
            int row = lr + i * 32;
            float4 av = *(const float4*)(A + (size_t)(m0 + row) * K + k0 + lc * 4);
            unsigned lo = (unsigned)f2bf(av.x) | ((unsigned)f2bf(av.y) << 16);
            unsigned hi = (unsigned)f2bf(av.z) | ((unsigned)f2bf(av.w) << 16);
            *(uint2*)&As[row][lc * 4] = make_uint2(lo, hi);
            int gr = n0 + row;
            float4 bv = make_float4(0.f, 0.f, 0.f, 0.f);
            if (gr < N) bv = *(const float4*)(B + (size_t)gr * K + k0 + lc * 4);
            lo = (unsigned)f2bf(bv.x) | ((unsigned)f2bf(bv.y) << 16);
            hi = (unsigned)f2bf(bv.z) | ((unsigned)f2bf(bv.w) << 16);
            *(uint2*)&Bs[row][lc * 4] = make_uint2(lo, hi);
        }
        __syncthreads();
        bf8_t af[4], bfr[4];
#pragma unroll
        for (int i = 0; i < 4; i++) {
            af[i]  = *(const bf8_t*)&As[wm * 64 + i * 16 + frow][fk];
            bfr[i] = *(const bf8_t*)&Bs[wn * 64 + i * 16 + frow][fk];
        }
#pragma unroll
        for (int i = 0; i < 4; i++)
#pragma unroll
            for (int j = 0; j < 4; j++)
                acc[i][j] = __builtin_amdgcn_mfma_f32_16x16x32_bf16(af[i], bfr[j], acc[i][j], 0, 0, 0);
        __syncthreads();
    }

    // epilogue: row = m0+wm*64+i*16+(lane>>4)*4+g  (A side), col = n0+wn*64+j*16+(lane&15) (B side)
    const int rbase = m0 + wm * 64 + ((lane >> 4) << 2);
#pragma unroll
    for (int j = 0; j < 4; j++) {
        int col = n0 + wn * 64 + j * 16 + (lane & 15);
        if (col < N) {
            float bsum = bias0[col] + (bias1 ? bias1[col] : 0.f);
#pragma unroll
            for (int i = 0; i < 4; i++) {
                int rb = rbase + i * 16;
#pragma unroll
                for (int g = 0; g < 4; g++)
                    C[(size_t)(rb + g) * N + col] = acc[i][j][g] + bsum;
            }
        }
    }
}

// ---------------- persistent LSTM scan ----------------
// 128 WGs x 256 threads. WG w owns h-outputs j in [w*8, w*8+8); holds 32 rows of
// W_hh (4 gates x 8 j) as bf16 in LDS. Sync through hs[] sentinel values.
__global__ __launch_bounds__(256, 1) void lstm_scan(const float* __restrict__ Whh,
                                                    const float* __restrict__ xg,
                                                    unsigned* __restrict__ hs) {
    extern __shared__ char smem[];
    unsigned short* Wl = (unsigned short*)smem;        // [32][1032] = 66048 B
    float* hl   = (float*)(smem + 66048);              // [1024]     -> 70144
    float* gbuf = (float*)(smem + 70144);              // [32]       -> 70272
    float* cbuf = (float*)(smem + 70272);              // [8]        -> 70304

    const int tid = threadIdx.x;
    const int wg  = blockIdx.x;

    // preload + convert W_hh rows for this WG
    for (int i = tid; i < 32 * 1024; i += 256) {
        int r = i >> 10, k = i & 1023;
        int R = ((r >> 3) << 10) + wg * 8 + (r & 7);
        Wl[r * 1032 + k] = f2bf(Whh[(size_t)R * 1024 + k]);
    }
    if (tid < 8) cbuf[tid] = 0.f;
    __syncthreads();

    const int r = tid >> 3;           // row 0..31
    const int s = tid & 7;            // k-slice 0..7
    const unsigned short* wrow = Wl + r * 1032;

    for (int t = 0; t < 2048; t++) {
        // acquire h_t into LDS
        if (t == 0) {
#pragma unroll
            for (int q = 0; q < 4; q++) hl[tid + (q << 8)] = 0.f;
        } else {
            const unsigned* src = hs + (size_t)(t - 1) * 1024;
#pragma unroll
            for (int q = 0; q < 4; q++) {
                int idx = tid + (q << 8);
                unsigned u = __hip_atomic_load(src + idx, __ATOMIC_RELAXED, __HIP_MEMORY_SCOPE_AGENT);
                while (u == SENT) {
                    __builtin_amdgcn_s_sleep(1);
                    u = __hip_atomic_load(src + idx, __ATOMIC_RELAXED, __HIP_MEMORY_SCOPE_AGENT);
                }
                hl[idx] = __uint_as_float(u);
            }
        }
        __syncthreads();

        // partial dot: row r, k in {s*8 + 64*i}
        float acc = 0.f;
#pragma unroll
        for (int i = 0; i < 16; i++) {
            int k = (s << 3) + (i << 6);
            uint4 wv = *(const uint4*)(wrow + k);
            float4 h0 = *(const float4*)(hl + k);
            float4 h1 = *(const float4*)(hl + k + 4);
            acc += bflo(wv.x) * h0.x + bfhi(wv.x) * h0.y
                 + bflo(wv.y) * h0.z + bfhi(wv.y) * h0.w
                 + bflo(wv.z) * h1.x + bfhi(wv.z) * h1.y
                 + bflo(wv.w) * h1.z + bfhi(wv.w) * h1.w;
        }
        acc += __shfl_down(acc, 4);
        acc += __shfl_down(acc, 2);
        acc += __shfl_down(acc, 1);
        if (s == 0) {
            int R = ((r >> 3) << 10) + wg * 8 + (r & 7);
            gbuf[r] = acc + xg[(size_t)t * 4096 + R];
        }
        __syncthreads();

        if (tid < 8) {
            float gi = sigm(gbuf[tid]);
            float gf = sigm(gbuf[8 + tid]);
            float gg = tanhf(gbuf[16 + tid]);
            float go = sigm(gbuf[24 + tid]);
            float c = gf * cbuf[tid] + gi * gg;
            cbuf[tid] = c;
            float h = go * tanhf(c);
            __hip_atomic_store(hs + (size_t)t * 1024 + wg * 8 + tid, __float_as_uint(h),
                               __ATOMIC_RELAXED, __HIP_MEMORY_SCOPE_AGENT);
        }
        __syncthreads();
    }
}

// ---------------- in-place log_softmax over rows of N ----------------
__global__ __launch_bounds__(256) void logsoftmax_rows(float* __restrict__ P, int N) {
    __shared__ float sm[4], sl[4], sfin;
    const int tid = threadIdx.x;
    float* p = P + (size_t)blockIdx.x * N;
    float m = -3.4e38f, l = 0.f;
    for (int i = tid; i < N; i += 256) {
        float x = p[i];
        float M = fmaxf(m, x);
        l = l * __expf(m - M) + __expf(x - M);
        m = M;
    }
    for (int off = 32; off; off >>= 1) {
        float m2 = __shfl_down(m, off);
        float l2 = __shfl_down(l, off);
        float M = fmaxf(m, m2);
        l = l * __expf(m - M) + l2 * __expf(m2 - M);
        m = M;
    }
    if ((tid & 63) == 0) { sm[tid >> 6] = m; sl[tid >> 6] = l; }
    __syncthreads();
    if (tid == 0) {
        m = sm[0]; l = sl[0];
        for (int w = 1; w < 4; w++) {
            float M = fmaxf(m, sm[w]);
            l = l * __expf(m - M) + sl[w] * __expf(sm[w] - M);
            m = M;
        }
        sfin = m + logf(l);
    }
    __syncthreads();
    float lse = sfin;
    for (int i = tid; i < N; i += 256) p[i] = p[i] - lse;
}

extern "C" void kernel_launch(void* const* d_in, const int* in_sizes, int n_in,
                              void* d_out, int out_size, void* d_ws, size_t ws_size,
                              hipStream_t stream) {
    const int*   sentence = (const int*)  d_in[0];
    const float* wte      = (const float*)d_in[1];
    const float* W_ih     = (const float*)d_in[2];
    const float* W_hh     = (const float*)d_in[3];
    const float* b_ih     = (const float*)d_in[4];
    const float* b_hh     = (const float*)d_in[5];
    const float* W_head   = (const float*)d_in[6];
    const float* b_head   = (const float*)d_in[7];
    float* out = (float*)d_out;

    char* ws = (char*)d_ws;
    float* xg  = (float*)ws;                          // 2048*4096*4 = 33,554,432
    float* emb = (float*)(ws + 33554432);             // 2048*1024*4 =  8,388,608
    float* hsf = (float*)(ws + 41943040);             // 2048*1024*4 =  8,388,608
    unsigned* hsu = (unsigned*)hsf;

    hipFuncSetAttribute(reinterpret_cast<const void*>(lstm_scan),
                        hipFuncAttributeMaxDynamicSharedMemorySize, 71680);

    fill_sent<<<2048, 256, 0, stream>>>(hsu);
    gather_emb<<<2048, 256, 0, stream>>>(sentence, wte, emb);

    dim3 g1(2048 / 128, 4096 / 128);   // (16, 32)
    gemm_bt<<<g1, 256, 0, stream>>>(emb, W_ih, b_ih, b_hh, xg, 2048, 4096, 1024);

    lstm_scan<<<128, 256, 70400, stream>>>(W_hh, xg, hsu);

    dim3 g2(2048 / 128, (50257 + 127) / 128);  // (16, 393)
    gemm_bt<<<g2, 256, 0, stream>>>(hsf, W_head, b_head, nullptr, out, 2048, 50257, 1024);

    logsoftmax_rows<<<2048, 256, 0, stream>>>(out, 50257);
}